// Round 2
// baseline (28403.073 us; speedup 1.0000x reference)
//
#include <hip/hip_runtime.h>

#define BB   64
#define TT   1024
#define II   256
#define HH   512
#define NBLK 32
#define NTHR 512
#define SLICE 16
#define WHH_STR 520
#define WIH_STR 264
#define CLIPV 5.0f

typedef __attribute__((ext_vector_type(8))) short short8;
typedef __attribute__((ext_vector_type(4))) float f32x4;

// ---------- bf16 helpers (RNE) ----------
__device__ __forceinline__ unsigned short f2bf(float f){
    unsigned u = __float_as_uint(f);
    u += 0x7fffu + ((u >> 16) & 1u);
    return (unsigned short)(u >> 16);
}
__device__ __forceinline__ float bf2f(unsigned short s){
    return __uint_as_float(((unsigned)s) << 16);
}
// split fp32 -> (hi,lo) bf16 pair packed in one dword (hi in low 16)
__device__ __forceinline__ unsigned packsplit(float f){
    unsigned short hi = f2bf(f);
    unsigned short lo = f2bf(f - bf2f(hi));
    return (unsigned)hi | ((unsigned)lo << 16);
}

__device__ __forceinline__ void unpack8(const uint4 a, const uint4 b, short8 &hi, short8 &lo){
    hi[0]=(short)a.x; lo[0]=(short)(a.x>>16);
    hi[1]=(short)a.y; lo[1]=(short)(a.y>>16);
    hi[2]=(short)a.z; lo[2]=(short)(a.z>>16);
    hi[3]=(short)a.w; lo[3]=(short)(a.w>>16);
    hi[4]=(short)b.x; lo[4]=(short)(b.x>>16);
    hi[5]=(short)b.y; lo[5]=(short)(b.y>>16);
    hi[6]=(short)b.z; lo[6]=(short)(b.z>>16);
    hi[7]=(short)b.w; lo[7]=(short)(b.w>>16);
}

#define SPLIT1(f, j) { float f_=(f); unsigned short h_=f2bf(f_); hi[j]=(short)h_; lo[j]=(short)f2bf(f_-bf2f(h_)); }
__device__ __forceinline__ void split8(const float4 a, const float4 b, short8 &hi, short8 &lo){
    SPLIT1(a.x,0) SPLIT1(a.y,1) SPLIT1(a.z,2) SPLIT1(a.w,3)
    SPLIT1(b.x,4) SPLIT1(b.y,5) SPLIT1(b.z,6) SPLIT1(b.w,7)
}
#undef SPLIT1

__device__ __forceinline__ f32x4 mfma(short8 a, short8 b, f32x4 c){
    return __builtin_amdgcn_mfma_f32_16x16x32_bf16(a, b, c, 0, 0, 0);
}

// ---------- LLC-coherent relaxed accessors (no bulk L2 wb/inv) ----------
// Relaxed agent-scope atomics compile to sc-flagged, L1/L2-bypassing accesses
// that are coherent at the LLC — same encoding the (working) flag loads use.
// Release ordering is provided structurally: __syncthreads() drains
// vmcnt(0) per thread BEFORE s_barrier, so all prior sc-stores are at the
// coherence point before any thread can reach the post-barrier flag add.
__device__ __forceinline__ uint4 aload4(const unsigned* p){
    const unsigned long long* q = (const unsigned long long*)p;
    unsigned long long a = __hip_atomic_load(q,   __ATOMIC_RELAXED, __HIP_MEMORY_SCOPE_AGENT);
    unsigned long long b = __hip_atomic_load(q+1, __ATOMIC_RELAXED, __HIP_MEMORY_SCOPE_AGENT);
    uint4 r; r.x=(unsigned)a; r.y=(unsigned)(a>>32); r.z=(unsigned)b; r.w=(unsigned)(b>>32);
    return r;
}
__device__ __forceinline__ void astore(unsigned* p, unsigned v){
    __hip_atomic_store(p, v, __ATOMIC_RELAXED, __HIP_MEMORY_SCOPE_AGENT);
}

// poll 32 flags (one per lane), RELAXED — no per-iteration cache invalidate.
// Called by wave 0 only; other waves are released by the following __syncthreads.
__device__ __forceinline__ void wait_flags(const unsigned* f, unsigned target){
    int lane = threadIdx.x & 63;
    const unsigned* p = f + (lane & 31);
    while (true){
        unsigned v = __hip_atomic_load(p, __ATOMIC_RELAXED, __HIP_MEMORY_SCOPE_AGENT);
        if (__all((int)(v >= target))) break;
        __builtin_amdgcn_s_sleep(1);
    }
}

// LDS: whh hi/lo + wih hi/lo + bias(64f) + nh1(1024f) + h_lds(1024f)
#define LDS_BYTES ((48*WHH_STR + 48*WIH_STR)*2*2 + 64*4 + 1024*4 + 1024*4)

extern "C" __global__ void pack_x_kernel(const float* __restrict__ x,
                                         unsigned* __restrict__ xp, int n){
    int idx = blockIdx.x * 256 + threadIdx.x;
    if (idx < n) xp[idx] = packsplit(x[idx]);
}

extern "C" __global__ void __launch_bounds__(NTHR, 2) gru_scan(
    const float* __restrict__ x,  const float* __restrict__ h0,
    const float* __restrict__ Wih, const float* __restrict__ bih,
    const float* __restrict__ Whh, const float* __restrict__ bhh,
    float* __restrict__ out, unsigned* __restrict__ ws,
    const unsigned* __restrict__ xp)
{
    extern __shared__ char smem[];
    unsigned short* whh_hi = (unsigned short*)smem;                // 48 x WHH_STR
    unsigned short* whh_lo = whh_hi + 48*WHH_STR;
    unsigned short* wih_hi = whh_lo + 48*WHH_STR;                  // 48 x WIH_STR
    unsigned short* wih_lo = wih_hi + 48*WIH_STR;
    float* biasL = (float*)(wih_lo + 48*WIH_STR);                  // 48 (padded 64)
    float* nh1   = biasL + 64;                                     // 64x16 fp32
    float* h_lds = nh1 + 1024;                                     // 64x16 fp32 (own-block h)

    unsigned* flagA = ws;           // 32 flags (128B line)
    unsigned* flagB = ws + 32;      // next line
    unsigned* hp    = ws + 128;     // packed h pairs, 64x512 dwords
    unsigned* rhp   = hp + BB*HH;   // packed r*h pairs

    const int tid = threadIdx.x;
    const int bb  = blockIdx.x;
    const int colBase = SLICE * bb;

    // ---- load weight slices to LDS as bf16 pairs ----
    for (int e = tid; e < 48*HH; e += NTHR){
        int r = e >> 9, k = e & (HH-1);
        int g = r >> 4, j = r & 15;
        int grow = g*HH + colBase + j;
        float v = Whh[grow*HH + k];
        unsigned short hv = f2bf(v);
        whh_hi[r*WHH_STR + k] = hv;
        whh_lo[r*WHH_STR + k] = f2bf(v - bf2f(hv));
    }
    for (int e = tid; e < 48*II; e += NTHR){
        int r = e >> 8, k = e & (II-1);
        int g = r >> 4, j = r & 15;
        int grow = g*HH + colBase + j;
        float v = Wih[grow*II + k];
        unsigned short hv = f2bf(v);
        wih_hi[r*WIH_STR + k] = hv;
        wih_lo[r*WIH_STR + k] = f2bf(v - bf2f(hv));
    }
    if (tid < 48){
        int g = tid >> 4, j = tid & 15;
        int grow = g*HH + colBase + j;
        biasL[tid] = bih[grow] + bhh[grow];
    }

    const int w = tid >> 6, lane = tid & 63;
    const int quad = lane >> 4, li = lane & 15;
    const int g = w >> 2, mt = w & 3;       // g: 0=z(+nx), 1=r ; phase B: g==kh
    const int am  = mt*16 + li;             // A-frag batch row
    const int cg  = colBase + li;           // owned gate column
    const int dm0 = mt*16 + quad*4;         // D-layout batch rows base

    // ---- publish initial h slice (coherent stores) + local mirrors ----
    for (int e = tid; e < BB*SLICE; e += NTHR){
        int m = e >> 4, c = e & 15;
        float v = h0[m*HH + colBase + c];
        astore(&hp[m*HH + colBase + c], packsplit(v));
        h_lds[m*16 + c] = v;
    }
    float hprev[4] = {0.f,0.f,0.f,0.f};
    if (g == 0){
        #pragma unroll
        for (int i = 0; i < 4; ++i) hprev[i] = h0[(size_t)(dm0+i)*HH + cg];
    }
    __syncthreads();   // drains vmcnt(0) per thread -> hp at LLC before flag
    if (tid == 0) __hip_atomic_fetch_add(flagB + bb, 1u, __ATOMIC_RELAXED, __HIP_MEMORY_SCOPE_AGENT);

    // loop-invariant biases in registers (off the post-barrier critical path)
    const float bsum = biasL[g*16 + li];
    const float bn   = biasL[32 + li];

    float zh[4], omz[4];
    f32x4 accNX;

    for (int t = 0; t < TT; ++t){
        // ============ phase A : x-part first (independent of other blocks) ============
        uint4 xbuf[16];
        {
            const char* xb;
            if (xp) xb = (const char*)(xp + ((size_t)am*TT + t)*II + quad*8);
            else    xb = (const char*)(x  + ((size_t)am*TT + t)*II + quad*8);
            #pragma unroll
            for (int kt = 0; kt < 8; ++kt){
                xbuf[2*kt]   = *(const uint4*)(xb + (size_t)kt*128);
                xbuf[2*kt+1] = *(const uint4*)(xb + (size_t)kt*128 + 16);
            }
        }
        f32x4 accG = {0.f,0.f,0.f,0.f};
        accNX = (f32x4){0.f,0.f,0.f,0.f};
        #pragma unroll
        for (int kt = 0; kt < 8; ++kt){
            short8 ah, al;
            if (xp) unpack8(xbuf[2*kt], xbuf[2*kt+1], ah, al);
            else {
                float4 f0 = *(const float4*)&xbuf[2*kt];
                float4 f1 = *(const float4*)&xbuf[2*kt+1];
                split8(f0, f1, ah, al);
            }
            int ko = kt*32 + quad*8;
            short8 bh = *(const short8*)(wih_hi + (g*16+li)*WIH_STR + ko);
            short8 bl = *(const short8*)(wih_lo + (g*16+li)*WIH_STR + ko);
            accG = mfma(ah, bh, accG);
            accG = mfma(ah, bl, accG);
            accG = mfma(al, bh, accG);
            if (g == 0){
                short8 nbh = *(const short8*)(wih_hi + (32+li)*WIH_STR + ko);
                short8 nbl = *(const short8*)(wih_lo + (32+li)*WIH_STR + ko);
                accNX = mfma(ah, nbh, accNX);
                accNX = mfma(ah, nbl, accNX);
                accNX = mfma(al, nbh, accNX);
            }
        }

        // ---- wait for h(t-1) from all blocks: wave 0 polls, HW barrier releases ----
        if (w == 0) wait_flags(flagB, (unsigned)(t+1));
        __syncthreads();
        __builtin_amdgcn_sched_barrier(0);

        // ---- h-part MFMAs (coherent LLC loads) ----
        #pragma unroll
        for (int kt = 0; kt < 16; ++kt){
            int ko = kt*32 + quad*8;
            uint4 p0 = aload4(hp + am*HH + ko);
            uint4 p1 = aload4(hp + am*HH + ko + 4);
            short8 ah, al; unpack8(p0, p1, ah, al);
            short8 bh = *(const short8*)(whh_hi + (g*16+li)*WHH_STR + ko);
            short8 bl = *(const short8*)(whh_lo + (g*16+li)*WHH_STR + ko);
            accG = mfma(ah, bh, accG);
            accG = mfma(ah, bl, accG);
            accG = mfma(al, bh, accG);
        }
        {
            #pragma unroll
            for (int i = 0; i < 4; ++i){
                // own-block h: registers (g==0) / LDS mirror (g==1) — no LLC round trip
                float hvf = (g == 0) ? hprev[i] : h_lds[(dm0+i)*16 + li];
                float gate = 1.f/(1.f + __expf(-(accG[i] + bsum)));
                if (g == 0){ zh[i] = gate*hvf; omz[i] = 1.f - gate; }
                else       { astore(&rhp[(dm0+i)*HH + cg], packsplit(gate*hvf)); }
            }
        }
        __syncthreads();   // drains rhp coherent stores before flag release
        if (tid == 0) __hip_atomic_fetch_add(flagA + bb, 1u, __ATOMIC_RELAXED, __HIP_MEMORY_SCOPE_AGENT);

        // ============ phase B : n, blend, publish h ============
        if (w == 0) wait_flags(flagA, (unsigned)(t+1));
        __syncthreads();
        __builtin_amdgcn_sched_barrier(0);

        f32x4 accN = (g == 0) ? accNX : (f32x4){0.f,0.f,0.f,0.f};
        #pragma unroll
        for (int kt8 = 0; kt8 < 8; ++kt8){
            int kt = g*8 + kt8;
            int ko = kt*32 + quad*8;
            uint4 p0 = aload4(rhp + am*HH + ko);
            uint4 p1 = aload4(rhp + am*HH + ko + 4);
            short8 ah, al; unpack8(p0, p1, ah, al);
            short8 bh = *(const short8*)(whh_hi + (32+li)*WHH_STR + ko);
            short8 bl = *(const short8*)(whh_lo + (32+li)*WHH_STR + ko);
            accN = mfma(ah, bh, accN);
            accN = mfma(ah, bl, accN);
            accN = mfma(al, bh, accN);
        }
        if (g == 1){
            #pragma unroll
            for (int i = 0; i < 4; ++i) nh1[(dm0+i)*16 + li] = accN[i];
        }
        __syncthreads();
        if (g == 0){
            #pragma unroll
            for (int i = 0; i < 4; ++i){
                float np = accN[i] + nh1[(dm0+i)*16 + li] + bn;
                float n  = tanhf(np);
                float hv = zh[i] + omz[i]*n;
                hv = fminf(fmaxf(hv, -CLIPV), CLIPV);
                hprev[i] = hv;
                astore(&hp[(dm0+i)*HH + cg], packsplit(hv));
                h_lds[(dm0+i)*16 + li] = hv;
            }
        }
        __syncthreads();   // drains hp coherent stores + h_lds before flag release
        if (tid == 0) __hip_atomic_fetch_add(flagB + bb, 1u, __ATOMIC_RELAXED, __HIP_MEMORY_SCOPE_AGENT);

        // off the inter-block critical path: HBM output writes from registers
        if (g == 0){
            #pragma unroll
            for (int i = 0; i < 4; ++i){
                out[((size_t)(dm0+i)*TT + t)*HH + cg] = hprev[i];
                if (t == TT-1) out[(size_t)BB*TT*HH + (size_t)(dm0+i)*HH + cg] = hprev[i];
            }
        }
    }
}

extern "C" void kernel_launch(void* const* d_in, const int* in_sizes, int n_in,
                              void* d_out, int out_size, void* d_ws, size_t ws_size,
                              hipStream_t stream) {
    const float* x   = (const float*)d_in[0];
    const float* h0  = (const float*)d_in[1];
    const float* Wih = (const float*)d_in[2];
    const float* bih = (const float*)d_in[3];
    const float* Whh = (const float*)d_in[4];
    const float* bhh = (const float*)d_in[5];
    float* out = (float*)d_out;
    unsigned* ws = (unsigned*)d_ws;

    // ws layout: [flags 512B][hp 128KB][rhp 128KB][optional packed x 64MB]
    const size_t base_bytes = 512 + 2*(size_t)BB*HH*4;
    const size_t xp_bytes   = (size_t)BB*TT*II*4;
    unsigned* xp = nullptr;
    if (ws_size >= base_bytes + xp_bytes){
        xp = ws + base_bytes/4;
        int n = BB*TT*II;
        pack_x_kernel<<<dim3((n + 255)/256), dim3(256), 0, stream>>>(x, xp, n);
    }
    hipMemsetAsync(d_ws, 0, 512, stream);  // zero barrier flags every launch
    (void)hipFuncSetAttribute((const void*)gru_scan,
                              hipFuncAttributeMaxDynamicSharedMemorySize,
                              (int)LDS_BYTES);
    gru_scan<<<dim3(NBLK), dim3(NTHR), LDS_BYTES, stream>>>(
        x, h0, Wih, bih, Whh, bhh, out, ws, xp);
}